// Round 1
// baseline (318.564 us; speedup 1.0000x reference)
//
#include <hip/hip_runtime.h>

// RNN_ENCODER: bidirectional LSTM, B=4096, T=18, NIN=300, NH=64.
// Pipeline: prep_wt (cast W -> bf16 [n][k] padded) ; gemm_in (gather-GEMM
// zx = emb @ [Wf|Wb] + bias, bf16 MFMA, out bf16) ; lstm_rec (18-step
// recurrence, h@U via MFMA, gates in-register, writes words_emb+sent_emb).

typedef __attribute__((ext_vector_type(4))) float f32x4;
typedef __attribute__((ext_vector_type(8))) unsigned short u16x8;
typedef __attribute__((ext_vector_type(4))) unsigned short u16x4;

#define KPAD 320
#define SENT_OFF 9437184      // 4096*128*18
#define ZX_BYTES 75497472UL   // 18*4096*512 * 2B

__device__ __forceinline__ unsigned short f2bf(float f) {
  unsigned int u = __builtin_bit_cast(unsigned int, f);
  u += 0x7fffu + ((u >> 16) & 1u);   // round-to-nearest-even
  return (unsigned short)(u >> 16);
}
__device__ __forceinline__ float bf2f(unsigned short s) {
  return __builtin_bit_cast(float, ((unsigned int)s) << 16);
}
__device__ __forceinline__ void mfma16(f32x4& acc, u16x8 a, u16x8 b) {
  // D = A(16x32) * B(32x16) + C. A row = lane&15, B col = lane&15,
  // k-map (kt*32 + 8g + e) used consistently for A and B so HW k-order cancels.
  asm volatile("v_mfma_f32_16x16x32_bf16 %0, %1, %2, %0"
               : "+v"(acc) : "v"(a), "v"(b));
}
__device__ __forceinline__ float sigm(float x) {
  return __builtin_amdgcn_rcpf(1.0f + __expf(-x));
}
__device__ __forceinline__ float tanhf_(float x) {
  return 1.0f - 2.0f * __builtin_amdgcn_rcpf(1.0f + __expf(2.0f * x));
}

// ---------------------------------------------------------------- prep_wt
// Wt[n][k] = W_dir[k][n] as bf16, n in [0,512) (0:256 fwd, 256:512 bwd),
// k zero-padded to 320.
__global__ __launch_bounds__(320) void prep_wt(const float* __restrict__ Wf,
                                               const float* __restrict__ Wb,
                                               unsigned short* __restrict__ Wt) {
  const int n = blockIdx.x;    // 512
  const int k = threadIdx.x;   // 320
  const float* W = (n < 256) ? Wf : Wb;
  const int col = n & 255;
  float v = (k < 300) ? W[k * 256 + col] : 0.0f;
  Wt[n * KPAD + k] = f2bf(v);
}

// ---------------------------------------------------------------- gemm_in
// zx[t*4096+b][n] = emb(b,t) @ [Wf|Wb] + bias   (bf16 out, fp32 accum)
// 128x128 tile, 256 threads = 4 waves, each wave 64x64 (4x4 frags of 16x16).
__global__ __launch_bounds__(256) void gemm_in(const int* __restrict__ cap,
                                               const float* __restrict__ E,
                                               const unsigned short* __restrict__ Wt,
                                               const float* __restrict__ bfv,
                                               const float* __restrict__ bbv,
                                               unsigned short* __restrict__ zx) {
  __shared__ __align__(16) unsigned short Alds[128 * 40]; // 40-elem stride: 16B-aligned rows, spread banks
  __shared__ __align__(16) unsigned short Wlds[128 * 40];
  __shared__ int tok[128];

  const int tid = threadIdx.x;
  const int bid = blockIdx.x;          // 2304 = 576 m-blocks x 4 n-blocks
  const int nblk = bid & 3, mblk = bid >> 2;
  const int t = mblk >> 5;             // 32 m-blocks per t
  const int base_b = (mblk & 31) << 7;
  const int nbase = nblk << 7;

  if (tid < 128) tok[tid] = cap[(base_b + tid) * 18 + t];
  __syncthreads();

  const int lane = tid & 63, w = tid >> 6;
  const int wrow = w >> 1, wcol = w & 1;
  const int l15 = lane & 15, g = lane >> 4;

  f32x4 acc[4][4];
#pragma unroll
  for (int ni = 0; ni < 4; ni++) {
    const int n = nbase + wcol * 64 + ni * 16 + l15;
    const float bv = (n < 256) ? bfv[n] : bbv[n - 256];
#pragma unroll
    for (int mi = 0; mi < 4; mi++) acc[mi][ni] = (f32x4){bv, bv, bv, bv};
  }

  const int srow = tid >> 1, shalf = tid & 1;        // A staging: 2 thr/row
  const float* erow = E + tok[srow] * 300;

  for (int kc = 0; kc < 10; kc++) {
    // ---- stage A tile [128 rows][32 k] with gather + cast
    const int k0 = kc * 32 + shalf * 16;
    float v[16];
    if (k0 + 16 <= 300) {
#pragma unroll
      for (int q4 = 0; q4 < 4; q4++) {
        f32x4 fv = *(const f32x4*)(erow + k0 + q4 * 4);
#pragma unroll
        for (int e = 0; e < 4; e++) v[q4 * 4 + e] = fv[e];
      }
    } else {
#pragma unroll
      for (int j = 0; j < 16; j++) {
        const int k = k0 + j;
        v[j] = (k < 300) ? erow[k] : 0.0f;
      }
    }
    u16x8 p0, p1;
#pragma unroll
    for (int e = 0; e < 8; e++) { p0[e] = f2bf(v[e]); p1[e] = f2bf(v[8 + e]); }
    *(u16x8*)&Alds[srow * 40 + shalf * 16] = p0;
    *(u16x8*)&Alds[srow * 40 + shalf * 16 + 8] = p1;

    // ---- stage W tile [128 n][32 k] (already bf16, transposed, padded)
#pragma unroll
    for (int rep = 0; rep < 2; rep++) {
      const int vv = tid + rep * 256;
      const int wr = vv >> 2, wp = vv & 3;
      u16x8 wv = *(const u16x8*)&Wt[(nbase + wr) * KPAD + kc * 32 + wp * 8];
      *(u16x8*)&Wlds[wr * 40 + wp * 8] = wv;
    }
    __syncthreads();

    u16x8 af[4], bf_[4];
#pragma unroll
    for (int mi = 0; mi < 4; mi++)
      af[mi] = *(const u16x8*)&Alds[(wrow * 64 + mi * 16 + l15) * 40 + g * 8];
#pragma unroll
    for (int ni = 0; ni < 4; ni++)
      bf_[ni] = *(const u16x8*)&Wlds[(wcol * 64 + ni * 16 + l15) * 40 + g * 8];
#pragma unroll
    for (int mi = 0; mi < 4; mi++)
#pragma unroll
      for (int ni = 0; ni < 4; ni++) mfma16(acc[mi][ni], af[mi], bf_[ni]);
    __syncthreads();
  }

  // ---- store: D cell (reg j, lane) -> row = 4g+j, col = l15 (m89-verified)
#pragma unroll
  for (int mi = 0; mi < 4; mi++) {
    const int mrow = wrow * 64 + mi * 16 + g * 4;
#pragma unroll
    for (int ni = 0; ni < 4; ni++) {
      const int n = nbase + wcol * 64 + ni * 16 + l15;
#pragma unroll
      for (int j = 0; j < 4; j++)
        zx[(t * 4096 + base_b + mrow + j) * 512 + n] = f2bf(acc[mi][ni][j]);
    }
  }
}

// ---------------------------------------------------------------- lstm_rec
// 512 blocks = 2 dirs x 256 chunks of 16 batch rows. 256 thr = 4 waves.
// Wave w owns units u = w*16 + (lane&15) for all 4 gates (n-tiles q*64+w*16),
// so i,f,g,o of one (row,u) land in one lane at the same reg index.
__global__ __launch_bounds__(256) void lstm_rec(const unsigned short* __restrict__ zx,
                                                const float* __restrict__ h0f,
                                                const float* __restrict__ c0f,
                                                const float* __restrict__ h0b,
                                                const float* __restrict__ c0b,
                                                const float* __restrict__ Uf,
                                                const float* __restrict__ Ub,
                                                float* __restrict__ out) {
  __shared__ __align__(16) unsigned short hl[16 * 72]; // 72-elem stride (144B rows)

  const int tid = threadIdx.x;
  const int bid = blockIdx.x;
  const int dir = bid & 1;
  const int base_b = (bid >> 1) << 4;
  const float* h0 = dir ? h0b : h0f;
  const float* c0 = dir ? c0b : c0f;
  const float* U = dir ? Ub : Uf;

  const int lane = tid & 63, w = tid >> 6;
  const int l15 = lane & 15, g = lane >> 4;
  const int u = w * 16 + l15;

  // U fragments in registers: ufr[gate][ktile], k = kt*32 + 8g + e
  u16x8 ufr[4][2];
#pragma unroll
  for (int q = 0; q < 4; q++)
#pragma unroll
    for (int kt = 0; kt < 2; kt++) {
      u16x8 tmp;
#pragma unroll
      for (int e = 0; e < 8; e++)
        tmp[e] = f2bf(U[(kt * 32 + g * 8 + e) * 256 + q * 64 + u]);
      ufr[q][kt] = tmp;
    }

  // c state: cells (row = 4g+j, unit u)
  float c[4];
#pragma unroll
  for (int j = 0; j < 4; j++) c[j] = c0[(base_b + g * 4 + j) * 64 + u];

  { // h0 -> LDS bf16
    const int r = tid >> 4, k4 = (tid & 15) * 4;
    f32x4 h4 = *(const f32x4*)&h0[(base_b + r) * 64 + k4];
    u16x4 hp;
#pragma unroll
    for (int e = 0; e < 4; e++) hp[e] = f2bf(h4[e]);
    *(u16x4*)&hl[r * 72 + k4] = hp;
  }
  __syncthreads();

  float hnew[4];
  for (int s = 0; s < 18; s++) {
    const int t = dir ? (17 - s) : s;
    // issue zx loads early (independent of h)
    float zvf[4][4];
#pragma unroll
    for (int q = 0; q < 4; q++)
#pragma unroll
      for (int j = 0; j < 4; j++)
        zvf[q][j] = bf2f(zx[(t * 4096 + base_b + g * 4 + j) * 512 +
                            dir * 256 + q * 64 + u]);
    // h fragments: A row = l15, k = kt*32 + 8g + e
    u16x8 hf[2];
#pragma unroll
    for (int kt = 0; kt < 2; kt++)
      hf[kt] = *(const u16x8*)&hl[l15 * 72 + kt * 32 + g * 8];

    f32x4 acc[4];
#pragma unroll
    for (int q = 0; q < 4; q++)
      acc[q] = (f32x4){zvf[q][0], zvf[q][1], zvf[q][2], zvf[q][3]};
#pragma unroll
    for (int q = 0; q < 4; q++)
#pragma unroll
      for (int kt = 0; kt < 2; kt++) mfma16(acc[q], hf[kt], ufr[q][kt]);

#pragma unroll
    for (int j = 0; j < 4; j++) {
      const float iv = sigm(acc[0][j]);
      const float fv = sigm(acc[1][j]);
      const float gv = tanhf_(acc[2][j]);
      const float ov = sigm(acc[3][j]);
      c[j] = fv * c[j] + iv * gv;
      const float hv = ov * tanhf_(c[j]);
      hnew[j] = hv;
      out[((base_b + g * 4 + j) * 128 + dir * 64 + u) * 18 + t] = hv;
    }
    __syncthreads();                 // all A-frag reads done
#pragma unroll
    for (int j = 0; j < 4; j++) hl[(g * 4 + j) * 72 + u] = f2bf(hnew[j]);
    __syncthreads();                 // h_new visible
  }
#pragma unroll
  for (int j = 0; j < 4; j++)
    out[SENT_OFF + (base_b + g * 4 + j) * 128 + dir * 64 + u] = hnew[j];
}

// ---------------------------------------------------------------- launcher
extern "C" void kernel_launch(void* const* d_in, const int* in_sizes, int n_in,
                              void* d_out, int out_size, void* d_ws, size_t ws_size,
                              hipStream_t stream) {
  const int* cap = (const int*)d_in[0];
  // d_in[1] = cap_lens (unused by reference)
  const float* h0f = (const float*)d_in[2];
  const float* c0f = (const float*)d_in[3];
  const float* h0b = (const float*)d_in[4];
  const float* c0b = (const float*)d_in[5];
  const float* E   = (const float*)d_in[6];
  const float* Wf  = (const float*)d_in[7];
  const float* Uf  = (const float*)d_in[8];
  const float* bf_ = (const float*)d_in[9];
  const float* Wb  = (const float*)d_in[10];
  const float* Ub  = (const float*)d_in[11];
  const float* bb_ = (const float*)d_in[12];
  float* out = (float*)d_out;

  unsigned short* zx = (unsigned short*)d_ws;                       // 75.5 MB
  unsigned short* Wt = (unsigned short*)((char*)d_ws + ZX_BYTES);   // 320 KB

  prep_wt<<<512, 320, 0, stream>>>(Wf, Wb, Wt);
  gemm_in<<<2304, 256, 0, stream>>>(cap, E, Wt, bf_, bb_, zx);
  lstm_rec<<<512, 256, 0, stream>>>(zx, h0f, c0f, h0b, c0b, Uf, Ub, out);
}

// Round 6
// 237.299 us; speedup vs baseline: 1.3425x; 1.3425x over previous
//
#include <hip/hip_runtime.h>

// RNN_ENCODER: bidirectional LSTM, B=4096, T=18, NIN=300, NH=64.
// = round-1 kernel (PASS, absmax 2.44e-4) with ONE change in lstm_rec:
// per-step scatter stores (4B @ 72B stride, 8x write amp, 328 MB) replaced by
// bf16 LDS history hist[t][row][unit] written in-loop (t-indexed, so the
// dir-reversal stays in-loop exactly as r1) + a coalesced f32x2 epilogue.
// gemm_in / prep_wt are VERBATIM round 1. No new unroll pragmas.

typedef __attribute__((ext_vector_type(4))) float f32x4;
typedef __attribute__((ext_vector_type(2))) float f32x2;
typedef __attribute__((ext_vector_type(8))) unsigned short u16x8;
typedef __attribute__((ext_vector_type(4))) unsigned short u16x4;

#define KPAD 320
#define SENT_OFF 9437184      // 4096*128*18
#define ZX_BYTES 75497472UL   // 18*4096*512 * 2B
#define HSTRIDE 68            // hist row-pad: spreads banks

__device__ __forceinline__ unsigned short f2bf(float f) {
  unsigned int u = __builtin_bit_cast(unsigned int, f);
  u += 0x7fffu + ((u >> 16) & 1u);   // round-to-nearest-even
  return (unsigned short)(u >> 16);
}
__device__ __forceinline__ float bf2f(unsigned short s) {
  return __builtin_bit_cast(float, ((unsigned int)s) << 16);
}
__device__ __forceinline__ void mfma16(f32x4& acc, u16x8 a, u16x8 b) {
  // A row = lane&15, B col = lane&15; k-map (kt*32 + 8g + e) used for BOTH
  // A and B so HW k-order cancels. C/D: col=lane&15, row=4*(lane>>4)+reg.
  asm volatile("v_mfma_f32_16x16x32_bf16 %0, %1, %2, %0"
               : "+v"(acc) : "v"(a), "v"(b));
}
__device__ __forceinline__ float sigm(float x) {
  return __builtin_amdgcn_rcpf(1.0f + __expf(-x));
}
__device__ __forceinline__ float tanhf_(float x) {
  return 1.0f - 2.0f * __builtin_amdgcn_rcpf(1.0f + __expf(2.0f * x));
}

// ---------------------------------------------------------------- prep_wt
// Wt[n][k] = W_dir[k][n] as bf16, n in [0,512) (0:256 fwd, 256:512 bwd),
// k zero-padded to 320.  (VERBATIM round 1)
__global__ __launch_bounds__(320) void prep_wt(const float* __restrict__ Wf,
                                               const float* __restrict__ Wb,
                                               unsigned short* __restrict__ Wt) {
  const int n = blockIdx.x;    // 512
  const int k = threadIdx.x;   // 320
  const float* W = (n < 256) ? Wf : Wb;
  const int col = n & 255;
  float v = (k < 300) ? W[k * 256 + col] : 0.0f;
  Wt[n * KPAD + k] = f2bf(v);
}

// ---------------------------------------------------------------- gemm_in
// zx[t*4096+b][n] = emb(b,t) @ [Wf|Wb] + bias   (bf16 out, fp32 accum)
// 128x128 tile, 256 threads = 4 waves, each wave 64x64 (4x4 frags of 16x16).
// (VERBATIM round 1)
__global__ __launch_bounds__(256) void gemm_in(const int* __restrict__ cap,
                                               const float* __restrict__ E,
                                               const unsigned short* __restrict__ Wt,
                                               const float* __restrict__ bfv,
                                               const float* __restrict__ bbv,
                                               unsigned short* __restrict__ zx) {
  __shared__ __align__(16) unsigned short Alds[128 * 40];
  __shared__ __align__(16) unsigned short Wlds[128 * 40];
  __shared__ int tok[128];

  const int tid = threadIdx.x;
  const int bid = blockIdx.x;          // 2304 = 576 m-blocks x 4 n-blocks
  const int nblk = bid & 3, mblk = bid >> 2;
  const int t = mblk >> 5;             // 32 m-blocks per t
  const int base_b = (mblk & 31) << 7;
  const int nbase = nblk << 7;

  if (tid < 128) tok[tid] = cap[(base_b + tid) * 18 + t];
  __syncthreads();

  const int lane = tid & 63, w = tid >> 6;
  const int wrow = w >> 1, wcol = w & 1;
  const int l15 = lane & 15, g = lane >> 4;

  f32x4 acc[4][4];
#pragma unroll
  for (int ni = 0; ni < 4; ni++) {
    const int n = nbase + wcol * 64 + ni * 16 + l15;
    const float bv = (n < 256) ? bfv[n] : bbv[n - 256];
#pragma unroll
    for (int mi = 0; mi < 4; mi++) acc[mi][ni] = (f32x4){bv, bv, bv, bv};
  }

  const int srow = tid >> 1, shalf = tid & 1;        // A staging: 2 thr/row
  const float* erow = E + tok[srow] * 300;

  for (int kc = 0; kc < 10; kc++) {
    // ---- stage A tile [128 rows][32 k] with gather + cast
    const int k0 = kc * 32 + shalf * 16;
    float v[16];
    if (k0 + 16 <= 300) {
#pragma unroll
      for (int q4 = 0; q4 < 4; q4++) {
        f32x4 fv = *(const f32x4*)(erow + k0 + q4 * 4);
#pragma unroll
        for (int e = 0; e < 4; e++) v[q4 * 4 + e] = fv[e];
      }
    } else {
#pragma unroll
      for (int j = 0; j < 16; j++) {
        const int k = k0 + j;
        v[j] = (k < 300) ? erow[k] : 0.0f;
      }
    }
    u16x8 p0, p1;
#pragma unroll
    for (int e = 0; e < 8; e++) { p0[e] = f2bf(v[e]); p1[e] = f2bf(v[8 + e]); }
    *(u16x8*)&Alds[srow * 40 + shalf * 16] = p0;
    *(u16x8*)&Alds[srow * 40 + shalf * 16 + 8] = p1;

    // ---- stage W tile [128 n][32 k] (already bf16, transposed, padded)
#pragma unroll
    for (int rep = 0; rep < 2; rep++) {
      const int vv = tid + rep * 256;
      const int wr = vv >> 2, wp = vv & 3;
      u16x8 wv = *(const u16x8*)&Wt[(nbase + wr) * KPAD + kc * 32 + wp * 8];
      *(u16x8*)&Wlds[wr * 40 + wp * 8] = wv;
    }
    __syncthreads();

    u16x8 af[4], bf_[4];
#pragma unroll
    for (int mi = 0; mi < 4; mi++)
      af[mi] = *(const u16x8*)&Alds[(wrow * 64 + mi * 16 + l15) * 40 + g * 8];
#pragma unroll
    for (int ni = 0; ni < 4; ni++)
      bf_[ni] = *(const u16x8*)&Wlds[(wcol * 64 + ni * 16 + l15) * 40 + g * 8];
#pragma unroll
    for (int mi = 0; mi < 4; mi++)
#pragma unroll
      for (int ni = 0; ni < 4; ni++) mfma16(acc[mi][ni], af[mi], bf_[ni]);
    __syncthreads();
  }

  // ---- store: D cell (reg j, lane) -> row = 4g+j, col = l15
#pragma unroll
  for (int mi = 0; mi < 4; mi++) {
    const int mrow = wrow * 64 + mi * 16 + g * 4;
#pragma unroll
    for (int ni = 0; ni < 4; ni++) {
      const int n = nbase + wcol * 64 + ni * 16 + l15;
#pragma unroll
      for (int j = 0; j < 4; j++)
        zx[(t * 4096 + base_b + mrow + j) * 512 + n] = f2bf(acc[mi][ni][j]);
    }
  }
}

// ---------------------------------------------------------------- lstm_rec
// 512 blocks = 2 dirs x 256 chunks of 16 batch rows. 256 thr = 4 waves.
// Loop body identical to round 1 EXCEPT: the per-step global scatter store
// is replaced by a bf16 LDS history write hist[t][row][u]; a new epilogue
// dumps hist as contiguous 72B runs.
__global__ __launch_bounds__(256) void lstm_rec(const unsigned short* __restrict__ zx,
                                                const float* __restrict__ h0f,
                                                const float* __restrict__ c0f,
                                                const float* __restrict__ h0b,
                                                const float* __restrict__ c0b,
                                                const float* __restrict__ Uf,
                                                const float* __restrict__ Ub,
                                                float* __restrict__ out) {
  __shared__ __align__(16) unsigned short hl[16 * 72]; // 144B row stride (r1)
  __shared__ __align__(16) unsigned short hist[18 * 16 * HSTRIDE]; // [t][row][u]

  const int tid = threadIdx.x;
  const int bid = blockIdx.x;
  const int dir = bid & 1;
  const int base_b = (bid >> 1) << 4;
  const float* h0 = dir ? h0b : h0f;
  const float* c0 = dir ? c0b : c0f;
  const float* U = dir ? Ub : Uf;

  const int lane = tid & 63, w = tid >> 6;
  const int l15 = lane & 15, g = lane >> 4;
  const int u = w * 16 + l15;

  // U fragments in registers: k = kt*32 + 8g + e (same map as A frags)
  u16x8 ufr[4][2];
#pragma unroll
  for (int q = 0; q < 4; q++)
#pragma unroll
    for (int kt = 0; kt < 2; kt++) {
      u16x8 tmp;
#pragma unroll
      for (int e = 0; e < 8; e++)
        tmp[e] = f2bf(U[(kt * 32 + g * 8 + e) * 256 + q * 64 + u]);
      ufr[q][kt] = tmp;
    }

  // c state: cells (row = 4g+j, unit u)
  float c[4];
#pragma unroll
  for (int j = 0; j < 4; j++) c[j] = c0[(base_b + g * 4 + j) * 64 + u];

  { // h0 -> LDS bf16
    const int r = tid >> 4, k4 = (tid & 15) * 4;
    f32x4 h4 = *(const f32x4*)&h0[(base_b + r) * 64 + k4];
    u16x4 hp;
#pragma unroll
    for (int e = 0; e < 4; e++) hp[e] = f2bf(h4[e]);
    *(u16x4*)&hl[r * 72 + k4] = hp;
  }
  __syncthreads();

  float hnew[4];
  for (int s = 0; s < 18; s++) {
    const int t = dir ? (17 - s) : s;
    // zx reads: r1 layout, r1 addressing (scalar bf16)
    float zvf[4][4];
#pragma unroll
    for (int q = 0; q < 4; q++)
#pragma unroll
      for (int j = 0; j < 4; j++)
        zvf[q][j] = bf2f(zx[(t * 4096 + base_b + g * 4 + j) * 512 +
                            dir * 256 + q * 64 + u]);
    // h fragments: A row = l15, k = kt*32 + 8g + e
    u16x8 hf[2];
#pragma unroll
    for (int kt = 0; kt < 2; kt++)
      hf[kt] = *(const u16x8*)&hl[l15 * 72 + kt * 32 + g * 8];

    f32x4 acc[4];
#pragma unroll
    for (int q = 0; q < 4; q++)
      acc[q] = (f32x4){zvf[q][0], zvf[q][1], zvf[q][2], zvf[q][3]};
#pragma unroll
    for (int q = 0; q < 4; q++)
#pragma unroll
      for (int kt = 0; kt < 2; kt++) mfma16(acc[q], hf[kt], ufr[q][kt]);

#pragma unroll
    for (int j = 0; j < 4; j++) {
      const float iv = sigm(acc[0][j]);
      const float fv = sigm(acc[1][j]);
      const float gv = tanhf_(acc[2][j]);
      const float ov = sigm(acc[3][j]);
      c[j] = fv * c[j] + iv * gv;
      const float hv = ov * tanhf_(c[j]);
      hnew[j] = hv;
      hist[(t * 16 + g * 4 + j) * HSTRIDE + u] = f2bf(hv);  // t-indexed, like r1's store
    }
    __syncthreads();                 // all A-frag reads done (hist writes also before this)
#pragma unroll
    for (int j = 0; j < 4; j++) hl[(g * 4 + j) * 72 + u] = f2bf(hnew[j]);
    __syncthreads();                 // h_new visible
  }
  // loop ends with a barrier -> all hist writes visible to all threads

  // ---- epilogue: thread owns row r = tid>>4, channels ch4..ch4+3
  {
    const int r = tid >> 4;              // 0..15
    const int ch4 = (tid & 15) * 4;      // local unit 0,4,...,60
    for (int cc = 0; cc < 4; cc++) {
      const int chl = ch4 + cc;
      float* dst = out + ((size_t)(base_b + r) * 128 + dir * 64 + chl) * 18;
      for (int p = 0; p < 9; p++) {
        f32x2 v2 = {bf2f(hist[((2 * p) * 16 + r) * HSTRIDE + chl]),
                    bf2f(hist[((2 * p + 1) * 16 + r) * HSTRIDE + chl])};
        *(f32x2*)(dst + 2 * p) = v2;
      }
    }
  }

  // sent_emb: final h (full f32), exactly as round 1
#pragma unroll
  for (int j = 0; j < 4; j++)
    out[SENT_OFF + (size_t)(base_b + g * 4 + j) * 128 + dir * 64 + u] = hnew[j];
}

// ---------------------------------------------------------------- launcher
extern "C" void kernel_launch(void* const* d_in, const int* in_sizes, int n_in,
                              void* d_out, int out_size, void* d_ws, size_t ws_size,
                              hipStream_t stream) {
  const int* cap = (const int*)d_in[0];
  // d_in[1] = cap_lens (unused by reference)
  const float* h0f = (const float*)d_in[2];
  const float* c0f = (const float*)d_in[3];
  const float* h0b = (const float*)d_in[4];
  const float* c0b = (const float*)d_in[5];
  const float* E   = (const float*)d_in[6];
  const float* Wf  = (const float*)d_in[7];
  const float* Uf  = (const float*)d_in[8];
  const float* bf_ = (const float*)d_in[9];
  const float* Wb  = (const float*)d_in[10];
  const float* Ub  = (const float*)d_in[11];
  const float* bb_ = (const float*)d_in[12];
  float* out = (float*)d_out;

  unsigned short* zx = (unsigned short*)d_ws;                       // 75.5 MB
  unsigned short* Wt = (unsigned short*)((char*)d_ws + ZX_BYTES);   // 320 KB

  prep_wt<<<512, 320, 0, stream>>>(Wf, Wb, Wt);
  gemm_in<<<2304, 256, 0, stream>>>(cap, E, Wt, bf_, bb_, zx);
  lstm_rec<<<512, 256, 0, stream>>>(zx, h0f, c0f, h0b, c0b, Uf, Ub, out);
}

// Round 9
// 218.342 us; speedup vs baseline: 1.4590x; 1.0868x over previous
//
#include <hip/hip_runtime.h>

// RNN_ENCODER: bidirectional LSTM, B=4096, T=18, NIN=300, NH=64.
// = round-6 PASS kernel (absmax 2.441e-4) + TWO isolated changes:
//  1. gemm_in: XCD-grouping bid swizzle (4 nblks of one mblk -> same XCD).
//  2. zx j-packed layout ((t*1024+(row>>2))*512+n)*4+(row&3): u16x4 store in
//     gemm, u16x4 coalesced reads in lstm. Bit-identical values.
// lstm_rec loop structure is VERBATIM r6 (single hl buffer, TWO barriers per
// step, no preload pipeline) -- r7's single-barrier pipeline is the prime
// suspect for its 6e-3 failure and is NOT included.

typedef __attribute__((ext_vector_type(4))) float f32x4;
typedef __attribute__((ext_vector_type(2))) float f32x2;
typedef __attribute__((ext_vector_type(8))) unsigned short u16x8;
typedef __attribute__((ext_vector_type(4))) unsigned short u16x4;

#define KPAD 320
#define SENT_OFF 9437184      // 4096*128*18
#define ZX_BYTES 75497472UL   // 18*4096*512 * 2B
#define HSTRIDE 68            // hist row-pad: spreads banks

__device__ __forceinline__ unsigned short f2bf(float f) {
  unsigned int u = __builtin_bit_cast(unsigned int, f);
  u += 0x7fffu + ((u >> 16) & 1u);   // round-to-nearest-even
  return (unsigned short)(u >> 16);
}
__device__ __forceinline__ float bf2f(unsigned short s) {
  return __builtin_bit_cast(float, ((unsigned int)s) << 16);
}
__device__ __forceinline__ void mfma16(f32x4& acc, u16x8 a, u16x8 b) {
  // A row = lane&15, B col = lane&15; k-map (kt*32 + 8g + e) used for BOTH
  // A and B so HW k-order cancels. C/D: col=lane&15, row=4*(lane>>4)+reg.
  asm volatile("v_mfma_f32_16x16x32_bf16 %0, %1, %2, %0"
               : "+v"(acc) : "v"(a), "v"(b));
}
__device__ __forceinline__ float sigm(float x) {
  return __builtin_amdgcn_rcpf(1.0f + __expf(-x));
}
__device__ __forceinline__ float tanhf_(float x) {
  return 1.0f - 2.0f * __builtin_amdgcn_rcpf(1.0f + __expf(2.0f * x));
}

// ---------------------------------------------------------------- prep_wt
// Wt[n][k] = W_dir[k][n] as bf16, n in [0,512) (0:256 fwd, 256:512 bwd),
// k zero-padded to 320.  (VERBATIM round 1)
__global__ __launch_bounds__(320) void prep_wt(const float* __restrict__ Wf,
                                               const float* __restrict__ Wb,
                                               unsigned short* __restrict__ Wt) {
  const int n = blockIdx.x;    // 512
  const int k = threadIdx.x;   // 320
  const float* W = (n < 256) ? Wf : Wb;
  const int col = n & 255;
  float v = (k < 300) ? W[k * 256 + col] : 0.0f;
  Wt[n * KPAD + k] = f2bf(v);
}

// ---------------------------------------------------------------- gemm_in
// zx = emb @ [Wf|Wb] + bias (bf16 out, fp32 accum), 128x128 tile, 4 waves.
// Changes vs r6: XCD-grouping swizzle; j-packed u16x4 store.
__global__ __launch_bounds__(256) void gemm_in(const int* __restrict__ cap,
                                               const float* __restrict__ E,
                                               const unsigned short* __restrict__ Wt,
                                               const float* __restrict__ bfv,
                                               const float* __restrict__ bbv,
                                               unsigned short* __restrict__ zx) {
  __shared__ __align__(16) unsigned short Alds[128 * 40];
  __shared__ __align__(16) unsigned short Wlds[128 * 40];
  __shared__ int tok[128];

  const int tid = threadIdx.x;
  // XCD-grouping swizzle: consecutive bids round-robin XCDs (bid&7 = xcd).
  // The 4 nblks of one mblk land at bids {xcd + 8*(4*ml+nblk)} -> same XCD,
  // so the shared 128-token A-gather is an L2 hit for 3 of 4 blocks.
  const int bid = blockIdx.x;          // 2304 = 576 m-blocks x 4 n-blocks
  const int xcd = bid & 7;
  const int idx = bid >> 3;            // 0..287
  const int nblk = idx & 3;
  const int mblk = (idx >> 2) * 8 + xcd;   // bijective: 576 = 72*8
  const int t = mblk >> 5;             // 32 m-blocks per t
  const int base_b = (mblk & 31) << 7;
  const int nbase = nblk << 7;

  if (tid < 128) tok[tid] = cap[(base_b + tid) * 18 + t];
  __syncthreads();

  const int lane = tid & 63, w = tid >> 6;
  const int wrow = w >> 1, wcol = w & 1;
  const int l15 = lane & 15, g = lane >> 4;

  f32x4 acc[4][4];
#pragma unroll
  for (int ni = 0; ni < 4; ni++) {
    const int n = nbase + wcol * 64 + ni * 16 + l15;
    const float bv = (n < 256) ? bfv[n] : bbv[n - 256];
#pragma unroll
    for (int mi = 0; mi < 4; mi++) acc[mi][ni] = (f32x4){bv, bv, bv, bv};
  }

  const int srow = tid >> 1, shalf = tid & 1;        // A staging: 2 thr/row
  const float* erow = E + tok[srow] * 300;

  for (int kc = 0; kc < 10; kc++) {
    // ---- stage A tile [128 rows][32 k] with gather + cast
    const int k0 = kc * 32 + shalf * 16;
    float v[16];
    if (k0 + 16 <= 300) {
#pragma unroll
      for (int q4 = 0; q4 < 4; q4++) {
        f32x4 fv = *(const f32x4*)(erow + k0 + q4 * 4);
#pragma unroll
        for (int e = 0; e < 4; e++) v[q4 * 4 + e] = fv[e];
      }
    } else {
#pragma unroll
      for (int j = 0; j < 16; j++) {
        const int k = k0 + j;
        v[j] = (k < 300) ? erow[k] : 0.0f;
      }
    }
    u16x8 p0, p1;
#pragma unroll
    for (int e = 0; e < 8; e++) { p0[e] = f2bf(v[e]); p1[e] = f2bf(v[8 + e]); }
    *(u16x8*)&Alds[srow * 40 + shalf * 16] = p0;
    *(u16x8*)&Alds[srow * 40 + shalf * 16 + 8] = p1;

    // ---- stage W tile [128 n][32 k] (already bf16, transposed, padded)
#pragma unroll
    for (int rep = 0; rep < 2; rep++) {
      const int vv = tid + rep * 256;
      const int wr = vv >> 2, wp = vv & 3;
      u16x8 wv = *(const u16x8*)&Wt[(nbase + wr) * KPAD + kc * 32 + wp * 8];
      *(u16x8*)&Wlds[wr * 40 + wp * 8] = wv;
    }
    __syncthreads();

    u16x8 af[4], bf_[4];
#pragma unroll
    for (int mi = 0; mi < 4; mi++)
      af[mi] = *(const u16x8*)&Alds[(wrow * 64 + mi * 16 + l15) * 40 + g * 8];
#pragma unroll
    for (int ni = 0; ni < 4; ni++)
      bf_[ni] = *(const u16x8*)&Wlds[(wcol * 64 + ni * 16 + l15) * 40 + g * 8];
#pragma unroll
    for (int mi = 0; mi < 4; mi++)
#pragma unroll
      for (int ni = 0; ni < 4; ni++) mfma16(acc[mi][ni], af[mi], bf_[ni]);
    __syncthreads();
  }

  // ---- store: D cell (reg j, lane) -> row = 4g+j, col = l15; j-packed u16x4
#pragma unroll
  for (int mi = 0; mi < 4; mi++) {
    const int mrow = wrow * 64 + mi * 16 + g * 4;   // multiple of 4
    const int r4 = (base_b + mrow) >> 2;
#pragma unroll
    for (int ni = 0; ni < 4; ni++) {
      const int n = nbase + wcol * 64 + ni * 16 + l15;
      u16x4 hv;
#pragma unroll
      for (int j = 0; j < 4; j++) hv[j] = f2bf(acc[mi][ni][j]);
      *(u16x4*)&zx[(((size_t)t * 1024 + r4) * 512 + n) * 4] = hv;
    }
  }
}

// ---------------------------------------------------------------- lstm_rec
// 512 blocks = 2 dirs x 256 chunks of 16 batch rows. 256 thr = 4 waves.
// VERBATIM r6 loop (single hl, two barriers per step, hist-LDS epilogue)
// EXCEPT the zx read uses the j-packed u16x4 layout.
__global__ __launch_bounds__(256) void lstm_rec(const unsigned short* __restrict__ zx,
                                                const float* __restrict__ h0f,
                                                const float* __restrict__ c0f,
                                                const float* __restrict__ h0b,
                                                const float* __restrict__ c0b,
                                                const float* __restrict__ Uf,
                                                const float* __restrict__ Ub,
                                                float* __restrict__ out) {
  __shared__ __align__(16) unsigned short hl[16 * 72]; // 144B row stride (r1)
  __shared__ __align__(16) unsigned short hist[18 * 16 * HSTRIDE]; // [t][row][u]

  const int tid = threadIdx.x;
  const int bid = blockIdx.x;
  const int dir = bid & 1;
  const int base_b = (bid >> 1) << 4;
  const float* h0 = dir ? h0b : h0f;
  const float* c0 = dir ? c0b : c0f;
  const float* U = dir ? Ub : Uf;

  const int lane = tid & 63, w = tid >> 6;
  const int l15 = lane & 15, g = lane >> 4;
  const int u = w * 16 + l15;

  // U fragments in registers: k = kt*32 + 8g + e (same map as A frags)
  u16x8 ufr[4][2];
#pragma unroll
  for (int q = 0; q < 4; q++)
#pragma unroll
    for (int kt = 0; kt < 2; kt++) {
      u16x8 tmp;
#pragma unroll
      for (int e = 0; e < 8; e++)
        tmp[e] = f2bf(U[(kt * 32 + g * 8 + e) * 256 + q * 64 + u]);
      ufr[q][kt] = tmp;
    }

  // c state: cells (row = 4g+j, unit u)
  float c[4];
#pragma unroll
  for (int j = 0; j < 4; j++) c[j] = c0[(base_b + g * 4 + j) * 64 + u];

  { // h0 -> LDS bf16
    const int r = tid >> 4, k4 = (tid & 15) * 4;
    f32x4 h4 = *(const f32x4*)&h0[(base_b + r) * 64 + k4];
    u16x4 hp;
#pragma unroll
    for (int e = 0; e < 4; e++) hp[e] = f2bf(h4[e]);
    *(u16x4*)&hl[r * 72 + k4] = hp;
  }
  __syncthreads();

  const int r4base = (base_b >> 2) + g;
  float hnew[4];
  for (int s = 0; s < 18; s++) {
    const int t = dir ? (17 - s) : s;
    // zx reads: j-packed layout, 8B/lane coalesced
    u16x4 zv[4];
#pragma unroll
    for (int q = 0; q < 4; q++)
      zv[q] = *(const u16x4*)&zx[(((size_t)t * 1024 + r4base) * 512 +
                                  dir * 256 + q * 64 + u) * 4];
    // h fragments: A row = l15, k = kt*32 + 8g + e
    u16x8 hf[2];
#pragma unroll
    for (int kt = 0; kt < 2; kt++)
      hf[kt] = *(const u16x8*)&hl[l15 * 72 + kt * 32 + g * 8];

    f32x4 acc[4];
#pragma unroll
    for (int q = 0; q < 4; q++)
      acc[q] = (f32x4){bf2f(zv[q][0]), bf2f(zv[q][1]),
                       bf2f(zv[q][2]), bf2f(zv[q][3])};
#pragma unroll
    for (int q = 0; q < 4; q++)
#pragma unroll
      for (int kt = 0; kt < 2; kt++) mfma16(acc[q], hf[kt], ufr[q][kt]);

#pragma unroll
    for (int j = 0; j < 4; j++) {
      const float iv = sigm(acc[0][j]);
      const float fv = sigm(acc[1][j]);
      const float gv = tanhf_(acc[2][j]);
      const float ov = sigm(acc[3][j]);
      c[j] = fv * c[j] + iv * gv;
      const float hv = ov * tanhf_(c[j]);
      hnew[j] = hv;
      hist[(t * 16 + g * 4 + j) * HSTRIDE + u] = f2bf(hv);  // t-indexed
    }
    __syncthreads();                 // all A-frag reads done
#pragma unroll
    for (int j = 0; j < 4; j++) hl[(g * 4 + j) * 72 + u] = f2bf(hnew[j]);
    __syncthreads();                 // h_new visible
  }
  // loop ends with a barrier -> all hist writes visible to all threads

  // ---- epilogue: thread owns row r = tid>>4, channels ch4..ch4+3 (r6 verbatim)
  {
    const int r = tid >> 4;              // 0..15
    const int ch4 = (tid & 15) * 4;      // local unit 0,4,...,60
    for (int cc = 0; cc < 4; cc++) {
      const int chl = ch4 + cc;
      float* dst = out + ((size_t)(base_b + r) * 128 + dir * 64 + chl) * 18;
      for (int p = 0; p < 9; p++) {
        f32x2 v2 = {bf2f(hist[((2 * p) * 16 + r) * HSTRIDE + chl]),
                    bf2f(hist[((2 * p + 1) * 16 + r) * HSTRIDE + chl])};
        *(f32x2*)(dst + 2 * p) = v2;
      }
    }
  }

  // sent_emb: final h (full f32)
#pragma unroll
  for (int j = 0; j < 4; j++)
    out[SENT_OFF + (size_t)(base_b + g * 4 + j) * 128 + dir * 64 + u] = hnew[j];
}

// ---------------------------------------------------------------- launcher
extern "C" void kernel_launch(void* const* d_in, const int* in_sizes, int n_in,
                              void* d_out, int out_size, void* d_ws, size_t ws_size,
                              hipStream_t stream) {
  const int* cap = (const int*)d_in[0];
  // d_in[1] = cap_lens (unused by reference)
  const float* h0f = (const float*)d_in[2];
  const float* c0f = (const float*)d_in[3];
  const float* h0b = (const float*)d_in[4];
  const float* c0b = (const float*)d_in[5];
  const float* E   = (const float*)d_in[6];
  const float* Wf  = (const float*)d_in[7];
  const float* Uf  = (const float*)d_in[8];
  const float* bf_ = (const float*)d_in[9];
  const float* Wb  = (const float*)d_in[10];
  const float* Ub  = (const float*)d_in[11];
  const float* bb_ = (const float*)d_in[12];
  float* out = (float*)d_out;

  unsigned short* zx = (unsigned short*)d_ws;                       // 75.5 MB
  unsigned short* Wt = (unsigned short*)((char*)d_ws + ZX_BYTES);   // 320 KB

  prep_wt<<<512, 320, 0, stream>>>(Wf, Wb, Wt);
  gemm_in<<<2304, 256, 0, stream>>>(cap, E, Wt, bf_, bb_, zx);
  lstm_rec<<<512, 256, 0, stream>>>(zx, h0f, c0f, h0b, c0b, Uf, Ub, out);
}